// Round 8
// baseline (110.907 us; speedup 1.0000x reference)
//
#include <hip/hip_runtime.h>
#include <stdint.h>

#define EPS 1e-6f
constexpr int B = 16, C = 26, H = 256, W = 256;
constexpr int CHW  = C * H * W;   // 1,703,936
constexpr int CHW4 = CHW / 4;     // 425,984 float4s per batch
constexpr int HW2  = 2 * H * W;   // 131,072
constexpr int P = 20, K = 2, E = 26;
constexpr int NBPB = 128;         // focal blocks per batch
constexpr int ITER = 13;          // per-thread float4 iterations
constexpr int CHUNK = ITER * 256; // 3328 float4s per block per stream
static_assert(NBPB * CHUNK == CHW4, "exact tiling");
constexpr int TOTAL_BLOCKS = (NBPB + 1) * B;  // 2064

// ws layout (floats)
constexpr int WS_PARTIALS = 0;                    // [B][NBPB][4]
constexpr int WS_HW  = B * NBPB * 4;              // [B][2]
constexpr int WS_PP  = WS_HW + B * 2;             // [B][P]
constexpr int WS_PV  = WS_PP + B * P;             // [B][P]
constexpr int WS_CNT = WS_PV + B * P;             // 1 uint

typedef float f32x4 __attribute__((ext_vector_type(4)));

__device__ inline float waveReduceSum(float v) {
#pragma unroll
  for (int o = 32; o > 0; o >>= 1) v += __shfl_down(v, o, 64);
  return v;
}

__device__ inline float halfReduceSum(float v) {  // width-32 reduce
#pragma unroll
  for (int o = 16; o > 0; o >>= 1) v += __shfl_xor(v, o, 32);
  return v;
}

// Single fused kernel. grid (NBPB+1, B) x 256.
//  - blocks x<NBPB: focal partial over a contiguous 52 KB chunk (r4 structure)
//  - block x==NBPB: hw L1 + bu tag gathers for batch b (overlapped)
//  - last block to finish (device-scope counter) finalizes all 48 outputs.
__global__ __launch_bounds__(256) void fused_loss_kernel(
    const f32x4* __restrict__ pred, const f32x4* __restrict__ gt,
    const float* __restrict__ hw_pred, const float* __restrict__ hw_gt,
    const float* __restrict__ bu_pred, const float* __restrict__ bu_gt,
    float* __restrict__ ws, float* __restrict__ out) {
  const int b = blockIdx.y;
  float* partials = ws + WS_PARTIALS;
  float* hw_res   = ws + WS_HW;
  float* bu_pp    = ws + WS_PP;
  float* bu_pv    = ws + WS_PV;
  unsigned int* cnt = (unsigned int*)(ws + WS_CNT);
  const int t = threadIdx.x, wave = t >> 6, lane = t & 63;

  if (blockIdx.x == NBPB) {
    // ---------------- aux block: hw + bu for batch b ----------------
    if (wave == 0) {
      float contrib = 0.f;
      bool wv = false;
      if (lane < P * K) {
        const float* g3 = hw_gt + ((size_t)(b * P * K + lane)) * 3;
        float val = g3[0];
        int idx = (int)g3[1];
        wv = g3[2] > 0.f;
        float gvv = hw_pred[(size_t)b * HW2 + idx];
        contrib = wv ? fabsf(gvv - val) : 0.f;
      }
      unsigned long long m = __ballot(wv);
      float l1 = waveReduceSum(contrib);
      if (lane == 0) {
        unsigned long long mm = (m | (m >> 1)) & 0x5555555555ULL;
        hw_res[b * 2 + 0] = l1;
        hw_res[b * 2 + 1] = (float)__popcll(mm);
      }
    }
    const int half = lane >> 5, l = lane & 31;
#pragma unroll
    for (int pbase = 0; pbase < P; pbase += 8) {
      int p = pbase + wave * 2 + half;
      float plp = 0.f, nlp = 0.f, npp = 0.f;
      bool mv = false;
      if (p < P && l < E) {
        const float* g3 = bu_gt + ((size_t)((b * P + p) * E + l)) * 3;
        float val = g3[0];
        int idx = (int)g3[1];
        mv = g3[2] > 0.f;
        float x = bu_pred[(size_t)b * CHW + idx];
        float gv = __builtin_amdgcn_rcpf(1.f + __expf(-x));
        if (mv) {
          if (val == 1.0f) {
            float o = 1.f - gv;
            plp = __logf(gv + EPS) * o * o;
            npp = 1.f;
          } else {
            nlp = __logf(1.f - gv + EPS) * gv * gv;
          }
        }
      }
      plp = halfReduceSum(plp);
      nlp = halfReduceSum(nlp);
      npp = halfReduceSum(npp);
      unsigned long long m = __ballot(mv);
      bool any = half ? ((m >> 32) != 0ULL) : ((m & 0xffffffffULL) != 0ULL);
      if (l == 0 && p < P) {
        float per = (npp == 0.f) ? -nlp : -(plp + nlp);
        float pv = any ? 1.f : 0.f;
        bu_pp[b * P + p] = per * pv;
        bu_pv[b * P + p] = pv;
      }
    }
  } else {
    // ---------------- focal block ----------------
    const size_t base = (size_t)b * CHW4 + (size_t)blockIdx.x * CHUNK;
    const f32x4* pp = pred + base;
    const f32x4* gg = gt + base;

    f32x4 xc = pp[t];
    f32x4 gc = gg[t];

    float pl = 0.f, nl = 0.f, npos = 0.f;
#pragma unroll
    for (int it = 0; it < ITER; ++it) {
      f32x4 xn, gn;
      if (it + 1 < ITER) {
        xn = pp[(it + 1) * 256 + t];
        gn = gg[(it + 1) * 256 + t];
      }
#pragma unroll
      for (int j = 0; j < 4; ++j) {
        float x = xc[j], g = gc[j];
        float p = __builtin_amdgcn_rcpf(1.f + __expf(-x));
        bool pos = (g == 1.0f);
        float og = 1.f - g;
        float og2 = og * og;
        float omp = 1.f - p;
        // neg weight (1-g)^4 is 0 at g==1, so one selected log serves both
        float arg = pos ? (p + EPS) : (1.f - p + EPS);
        float wt  = pos ? (omp * omp) : (p * p * (og2 * og2));
        float lw  = __logf(arg) * wt;
        pl   += pos ? lw : 0.f;
        nl   += pos ? 0.f : lw;
        npos += pos ? 1.f : 0.f;
      }
      if (it + 1 < ITER) { xc = xn; gc = gn; }
    }

    pl = waveReduceSum(pl);
    nl = waveReduceSum(nl);
    npos = waveReduceSum(npos);
    __shared__ float s[3][4];
    if (lane == 0) { s[0][wave] = pl; s[1][wave] = nl; s[2][wave] = npos; }
    __syncthreads();
    if (t == 0) {
      float* o = partials + ((size_t)b * NBPB + blockIdx.x) * 4;
      o[0] = s[0][0] + s[0][1] + s[0][2] + s[0][3];
      o[1] = s[1][0] + s[1][1] + s[1][2] + s[1][3];
      o[2] = s[2][0] + s[2][1] + s[2][2] + s[2][3];
      o[3] = 0.f;
    }
  }

  // ---------------- last-block-done finalize ----------------
  __syncthreads();
  __shared__ unsigned int s_old;
  if (t == 0) {
    __threadfence();  // release: partials/aux visible device-wide
    s_old = atomicAdd(cnt, 1u);
  }
  __syncthreads();
  if (s_old != TOTAL_BLOCKS - 1) return;
  __threadfence();  // acquire: see all other blocks' writes

  // 4 waves x 4 batches each; fixed read order -> deterministic
  for (int bb = wave; bb < B; bb += 4) {
    const float* pb = partials + (size_t)bb * NBPB * 4;
    float pl = 0.f, nl = 0.f, np = 0.f;
#pragma unroll
    for (int r = 0; r < 2; ++r) {
      int i = lane * 2 + r;  // 0..127
      pl += pb[i * 4 + 0];
      nl += pb[i * 4 + 1];
      np += pb[i * 4 + 2];
    }
    pl = waveReduceSum(pl);
    nl = waveReduceSum(nl);
    np = waveReduceSum(np);
    float pp = (lane < P) ? bu_pp[bb * P + lane] : 0.f;
    float pv = (lane < P) ? bu_pv[bb * P + lane] : 0.f;
    pp = waveReduceSum(pp);
    pv = waveReduceSum(pv);
    if (lane == 0) {
      float hm = (np > 0.f) ? (-(pl + nl) / fmaxf(np, 1.f)) : -nl;
      out[bb] = hm * 1.0f;  // HM_FACTOR
      float l1 = hw_res[bb * 2 + 0], npe = hw_res[bb * 2 + 1];
      out[16 + bb] = ((npe > 0.f) ? l1 / fmaxf(npe, 1.f) : 0.f) * 0.1f;  // HW
      out[32 + bb] = (pp / fmaxf(pv, 1.f)) * 1.0f;  // BU_FACTOR
    }
  }
}

extern "C" void kernel_launch(void* const* d_in, const int* in_sizes, int n_in,
                              void* d_out, int out_size, void* d_ws, size_t ws_size,
                              hipStream_t stream) {
  const float* hm_pred = (const float*)d_in[0];
  const float* hm_gt   = (const float*)d_in[1];
  const float* hw_pred = (const float*)d_in[2];
  const float* hw_gt   = (const float*)d_in[3];
  const float* bu_pred = (const float*)d_in[4];
  const float* bu_gt   = (const float*)d_in[5];
  float* out = (float*)d_out;
  float* ws = (float*)d_ws;

  // zero the completion counter (capturable async memset, runs every replay)
  hipMemsetAsync((char*)d_ws + WS_CNT * sizeof(float), 0, sizeof(unsigned int),
                 stream);
  hipLaunchKernelGGL(fused_loss_kernel, dim3(NBPB + 1, B), dim3(256), 0,
                     stream, (const f32x4*)hm_pred, (const f32x4*)hm_gt,
                     hw_pred, hw_gt, bu_pred, bu_gt, ws, out);
}

// Round 9
// 43.483 us; speedup vs baseline: 2.5506x; 2.5506x over previous
//
#include <hip/hip_runtime.h>
#include <stdint.h>

#define EPS 1e-6f
constexpr int B = 16, C = 26, H = 256, W = 256;
constexpr int CHW  = C * H * W;   // 1,703,936
constexpr int CHW4 = CHW / 4;     // 425,984 float4s per batch
constexpr int HW2  = 2 * H * W;   // 131,072
constexpr int P = 20, K = 2, E = 26;
constexpr int NBPB = 128;         // focal blocks per batch
constexpr int ITER = 13;          // per-thread float4 iterations
constexpr int CHUNK = ITER * 256; // 3328 float4s per block per stream
static_assert(NBPB * CHUNK == CHW4, "exact tiling");

typedef float f32x4 __attribute__((ext_vector_type(4)));

__device__ inline float waveReduceSum(float v) {
#pragma unroll
  for (int o = 32; o > 0; o >>= 1) v += __shfl_down(v, o, 64);
  return v;
}

__device__ inline float halfReduceSum(float v) {  // width-32 reduce
#pragma unroll
  for (int o = 16; o > 0; o >>= 1) v += __shfl_xor(v, o, 32);
  return v;
}

// ---------------- Kernel 1: focal partials + aux (hw/bu) block ----------------
// grid (NBPB+1, B) x 256. Blocks 0..NBPB-1: contiguous-chunk focal reduction
// (round-4 structure: compiler-scheduled depth-2 rotation, VGPR~20, best
// measured). Block NBPB: hw L1 gather (wave 0) + bu tag gathers (all waves),
// overlapped under focal's 40 us instead of serialized after it.
__global__ __launch_bounds__(256) void focal_partial_kernel(
    const f32x4* __restrict__ pred, const f32x4* __restrict__ gt,
    const float* __restrict__ hw_pred, const float* __restrict__ hw_gt,
    const float* __restrict__ bu_pred, const float* __restrict__ bu_gt,
    float* __restrict__ ws) {
  const int b = blockIdx.y;
  float* partials = ws;                      // [B][NBPB][4]
  float* hw_res   = ws + B * NBPB * 4;       // [B][2]
  float* bu_pp    = hw_res + B * 2;          // [B][P]
  float* bu_pv    = bu_pp + B * P;           // [B][P]

  if (blockIdx.x == NBPB) {
    // ---------------- aux block: hw + bu for batch b ----------------
    const int t = threadIdx.x, wave = t >> 6, lane = t & 63;
    if (wave == 0) {
      float contrib = 0.f;
      bool wv = false;
      if (lane < P * K) {
        const float* g3 = hw_gt + ((size_t)(b * P * K + lane)) * 3;
        float val = g3[0];
        int idx = (int)g3[1];
        wv = g3[2] > 0.f;
        float gvv = hw_pred[(size_t)b * HW2 + idx];
        contrib = wv ? fabsf(gvv - val) : 0.f;
      }
      unsigned long long m = __ballot(wv);
      float l1 = waveReduceSum(contrib);
      if (lane == 0) {
        unsigned long long mm = (m | (m >> 1)) & 0x5555555555ULL;
        hw_res[b * 2 + 0] = l1;
        hw_res[b * 2 + 1] = (float)__popcll(mm);
      }
    }
    const int half = lane >> 5, l = lane & 31;
#pragma unroll
    for (int pbase = 0; pbase < P; pbase += 8) {
      int p = pbase + wave * 2 + half;
      float plp = 0.f, nlp = 0.f, npp = 0.f;
      bool mv = false;
      if (p < P && l < E) {
        const float* g3 = bu_gt + ((size_t)((b * P + p) * E + l)) * 3;
        float val = g3[0];
        int idx = (int)g3[1];
        mv = g3[2] > 0.f;
        float x = bu_pred[(size_t)b * CHW + idx];
        float gv = __builtin_amdgcn_rcpf(1.f + __expf(-x));
        if (mv) {
          if (val == 1.0f) {
            float o = 1.f - gv;
            plp = __logf(gv + EPS) * o * o;
            npp = 1.f;
          } else {
            nlp = __logf(1.f - gv + EPS) * gv * gv;
          }
        }
      }
      plp = halfReduceSum(plp);
      nlp = halfReduceSum(nlp);
      npp = halfReduceSum(npp);
      unsigned long long m = __ballot(mv);
      bool any = half ? ((m >> 32) != 0ULL) : ((m & 0xffffffffULL) != 0ULL);
      if (l == 0 && p < P) {
        float per = (npp == 0.f) ? -nlp : -(plp + nlp);
        float pv = any ? 1.f : 0.f;
        bu_pp[b * P + p] = per * pv;
        bu_pv[b * P + p] = pv;
      }
    }
    return;
  }

  // ---------------- focal block ----------------
  const size_t base = (size_t)b * CHW4 + (size_t)blockIdx.x * CHUNK;
  const f32x4* pp = pred + base;
  const f32x4* gg = gt + base;
  const int tid = threadIdx.x;

  f32x4 xc = pp[tid];
  f32x4 gc = gg[tid];

  float pl = 0.f, nl = 0.f, npos = 0.f;
#pragma unroll
  for (int it = 0; it < ITER; ++it) {
    f32x4 xn, gn;
    if (it + 1 < ITER) {
      xn = pp[(it + 1) * 256 + tid];
      gn = gg[(it + 1) * 256 + tid];
    }
#pragma unroll
    for (int j = 0; j < 4; ++j) {
      float x = xc[j], g = gc[j];
      float p = __builtin_amdgcn_rcpf(1.f + __expf(-x));
      bool pos = (g == 1.0f);
      float og = 1.f - g;
      float og2 = og * og;
      float omp = 1.f - p;
      // neg weight (1-g)^4 is 0 at g==1, so one selected log serves both
      float arg = pos ? (p + EPS) : (1.f - p + EPS);
      float wt  = pos ? (omp * omp) : (p * p * (og2 * og2));
      float lw  = __logf(arg) * wt;
      pl   += pos ? lw : 0.f;
      nl   += pos ? 0.f : lw;
      npos += pos ? 1.f : 0.f;
    }
    if (it + 1 < ITER) { xc = xn; gc = gn; }
  }

  pl = waveReduceSum(pl);
  nl = waveReduceSum(nl);
  npos = waveReduceSum(npos);
  __shared__ float s[3][4];
  int wave = threadIdx.x >> 6, lane = threadIdx.x & 63;
  if (lane == 0) { s[0][wave] = pl; s[1][wave] = nl; s[2][wave] = npos; }
  __syncthreads();
  if (threadIdx.x == 0) {
    float* o = partials + ((size_t)b * NBPB + blockIdx.x) * 4;
    o[0] = s[0][0] + s[0][1] + s[0][2] + s[0][3];
    o[1] = s[1][0] + s[1][1] + s[1][2] + s[1][3];
    o[2] = s[2][0] + s[2][1] + s[2][2] + s[2][3];
    o[3] = 0.f;
  }
}

// ---------------- Kernel 2: slim finalize ----------------
// grid (B) x 256. Waves 0-1: reduce NBPB focal partials. Wave 2: bu sums
// (parallel lane reads). Wave 3: hw scalars. Thread 0 combines.
__global__ __launch_bounds__(256) void tail_kernel(
    const float* __restrict__ ws, float* __restrict__ out) {
  const int b = blockIdx.x, t = threadIdx.x;
  const int wave = t >> 6, lane = t & 63;
  const float* partials = ws;
  const float* hw_res   = ws + B * NBPB * 4;
  const float* bu_pp    = hw_res + B * 2;
  const float* bu_pv    = bu_pp + B * P;

  __shared__ float sA[3][2];
  __shared__ float sBU[2];
  __shared__ float sHW[2];

  if (wave < 2) {  // phase A: 128 partials
    const float* o = partials + ((size_t)b * NBPB + t) * 4;
    float pl = o[0], nl = o[1], np = o[2];
    pl = waveReduceSum(pl);
    nl = waveReduceSum(nl);
    np = waveReduceSum(np);
    if (lane == 0) { sA[0][wave] = pl; sA[1][wave] = nl; sA[2][wave] = np; }
  } else if (wave == 2) {  // bu sums
    float pp = (lane < P) ? bu_pp[b * P + lane] : 0.f;
    float pv = (lane < P) ? bu_pv[b * P + lane] : 0.f;
    pp = waveReduceSum(pp);
    pv = waveReduceSum(pv);
    if (lane == 0) { sBU[0] = pp; sBU[1] = pv; }
  } else {  // hw scalars
    float v = (lane < 2) ? hw_res[b * 2 + lane] : 0.f;
    if (lane < 2) sHW[lane] = v;
  }
  __syncthreads();
  if (t == 0) {
    float PL = sA[0][0] + sA[0][1];
    float NL = sA[1][0] + sA[1][1];
    float NP = sA[2][0] + sA[2][1];
    float hm = (NP > 0.f) ? (-(PL + NL) / fmaxf(NP, 1.f)) : -NL;
    out[b] = hm * 1.0f;  // HM_FACTOR
    float l1 = sHW[0], npe = sHW[1];
    out[16 + b] = ((npe > 0.f) ? l1 / fmaxf(npe, 1.f) : 0.f) * 0.1f;  // HW_FACTOR
    out[32 + b] = (sBU[0] / fmaxf(sBU[1], 1.f)) * 1.0f;  // BU_FACTOR
  }
}

extern "C" void kernel_launch(void* const* d_in, const int* in_sizes, int n_in,
                              void* d_out, int out_size, void* d_ws, size_t ws_size,
                              hipStream_t stream) {
  const float* hm_pred = (const float*)d_in[0];
  const float* hm_gt   = (const float*)d_in[1];
  const float* hw_pred = (const float*)d_in[2];
  const float* hw_gt   = (const float*)d_in[3];
  const float* bu_pred = (const float*)d_in[4];
  const float* bu_gt   = (const float*)d_in[5];
  float* out = (float*)d_out;
  float* ws = (float*)d_ws;  // partials + hw_res + bu_pp + bu_pv

  hipLaunchKernelGGL(focal_partial_kernel, dim3(NBPB + 1, B), dim3(256), 0,
                     stream, (const f32x4*)hm_pred, (const f32x4*)hm_gt,
                     hw_pred, hw_gt, bu_pred, bu_gt, ws);
  hipLaunchKernelGGL(tail_kernel, dim3(B), dim3(256), 0, stream, ws, out);
}